// Round 6
// baseline (457.234 us; speedup 1.0000x reference)
//
#include <hip/hip_runtime.h>
#include <math.h>

#define B_ 8
#define S_ 1024
#define D_ 1024
#define H_ 16
#define DK_ 64
#define EPS_ 1e-5f

typedef __bf16 bf16_t;
typedef __bf16 bf16x8 __attribute__((ext_vector_type(8)));
typedef __bf16 bf16x4v __attribute__((ext_vector_type(4)));
typedef float  f32x4  __attribute__((ext_vector_type(4)));

__device__ __forceinline__ void gld16(const void* g, void* l) {
    __builtin_amdgcn_global_load_lds(
        (const __attribute__((address_space(1))) void*)g,
        (__attribute__((address_space(3))) void*)l, 16, 0, 0);
}

// ---------------------------------------------------------------------------
// prep: fused weight transpose+convert (z=0..4) and x f32->bf16 (z=5..36).
// ---------------------------------------------------------------------------
__global__ __launch_bounds__(256)
void prep(const float* __restrict__ x,
          const float* __restrict__ Wq, const float* __restrict__ Wk,
          const float* __restrict__ Wv, const float* __restrict__ W1,
          const float* __restrict__ W2, bf16_t* __restrict__ xb,
          bf16_t* __restrict__ WtQKV, bf16_t* __restrict__ Wt1,
          bf16_t* __restrict__ Wt2)
{
    __shared__ float tile[64][65];
    const int tid = threadIdx.x;
    const int z = blockIdx.z;

    if (z >= 5) {   // x convert
        const int blk = (z - 5) * 256 + blockIdx.y * 16 + blockIdx.x;
        const int i = (blk * 256 + tid) * 4;
        const float4 v = *(const float4*)(x + i);
        bf16x4v o = { (bf16_t)v.x, (bf16_t)v.y, (bf16_t)v.z, (bf16_t)v.w };
        *(bf16x4v*)(xb + i) = o;
        return;
    }

    const int n0 = blockIdx.x * 64, k0 = blockIdx.y * 64;
    const int col = tid & 63, r0 = tid >> 6;
    const float* src = (z == 0) ? Wq : (z == 1) ? Wk : (z == 2) ? Wv
                     : (z == 3) ? W1 : W2;
    #pragma unroll
    for (int i = 0; i < 16; i++) {
        const int row = r0 + i * 4;
        float v;
        if (z < 3)
            v = src[((size_t)(n0 >> 6) << 16) + (size_t)(k0 + row) * 64 + col];
        else
            v = src[(size_t)(k0 + row) * D_ + n0 + col];
        tile[row][col] = v;
    }
    __syncthreads();
    bf16_t* dst = (z < 3) ? (WtQKV + (size_t)z * D_ * D_)
                : (z == 3) ? Wt1 : Wt2;
    #pragma unroll
    for (int i = 0; i < 16; i++) {
        const int nr = r0 + i * 4;
        dst[(size_t)(n0 + nr) * D_ + k0 + col] = (bf16_t)tile[col][nr];
    }
}

// ---------------------------------------------------------------------------
// bf16 MFMA GEMM, m97 structure (128x128, BK=32, global_load_lds w=16,
// chunk-XOR swizzle). EPI: 0 plain; 1 +bias,relu,mask; 2 +bias,mask.
// ---------------------------------------------------------------------------
template<int EPI, typename OUT>
__global__ __launch_bounds__(256)
void gemm_mfma(const bf16_t* __restrict__ A, const bf16_t* __restrict__ Bw,
               const float* __restrict__ bias, const int* __restrict__ lens,
               OUT* __restrict__ C, int M, int N, int K)
{
    __shared__ bf16_t As[128 * 32];
    __shared__ bf16_t Bs[128 * 32];
    const int tid  = threadIdx.x;
    const int lane = tid & 63;
    const int w    = tid >> 6;
    const int quad = lane >> 4, l16 = lane & 15;
    const int wm = w & 1, wn = w >> 1;
    const int bn = blockIdx.x * 128, bm = blockIdx.y * 128;

    f32x4 acc[4][4];
    #pragma unroll
    for (int i = 0; i < 4; i++)
        #pragma unroll
        for (int j = 0; j < 4; j++)
            #pragma unroll
            for (int r = 0; r < 4; r++) acc[i][j][r] = 0.f;

    const int fsw = (quad ^ (l16 ^ (l16 >> 2))) & 3;

    for (int k0 = 0; k0 < K; k0 += 32) {
        #pragma unroll
        for (int j = 0; j < 2; j++) {
            const int chunk = j * 256 + tid;
            const int m = chunk >> 2, cs = chunk & 3;
            const int cg = cs ^ ((m ^ (m >> 2)) & 3);
            gld16(A + (size_t)(bm + m) * K + k0 + cg * 8,
                  (char*)As + (size_t)(j * 256 + w * 64) * 16);
            gld16(Bw + (size_t)(bn + m) * K + k0 + cg * 8,
                  (char*)Bs + (size_t)(j * 256 + w * 64) * 16);
        }
        __syncthreads();

        bf16x8 a[4], b[4];
        #pragma unroll
        for (int i = 0; i < 4; i++)
            a[i] = *(const bf16x8*)&As[(wm * 64 + i * 16 + l16) * 32 + fsw * 8];
        #pragma unroll
        for (int j = 0; j < 4; j++)
            b[j] = *(const bf16x8*)&Bs[(wn * 64 + j * 16 + l16) * 32 + fsw * 8];
        #pragma unroll
        for (int i = 0; i < 4; i++)
            #pragma unroll
            for (int j = 0; j < 4; j++)
                acc[i][j] = __builtin_amdgcn_mfma_f32_16x16x32_bf16(a[i], b[j], acc[i][j], 0, 0, 0);
        __syncthreads();
    }

    #pragma unroll
    for (int i = 0; i < 4; i++) {
        #pragma unroll
        for (int r = 0; r < 4; r++) {
            const int m = bm + wm * 64 + i * 16 + quad * 4 + r;
            float keep = 1.f;
            if (EPI != 0) {
                const int s = m & (S_ - 1);
                const int bb = m >> 10;
                keep = (s < lens[bb]) ? 1.f : 0.f;
            }
            #pragma unroll
            for (int j = 0; j < 4; j++) {
                const int n = bn + wn * 64 + j * 16 + l16;
                float v = acc[i][j][r];
                if (EPI != 0) {
                    v += bias[n];
                    if (EPI == 1) v = fmaxf(v, 0.f);
                    v *= keep;
                }
                C[(size_t)m * N + n] = (OUT)v;
            }
        }
    }
}

// ---------------------------------------------------------------------------
// bf16 MFMA flash attention, BARRIER-FREE. V is pre-transposed globally
// (VT[h*64+d][token], produced by an operand-swapped gemm_mfma), so PV
// A-frags are contiguous global b128 loads -> no Vt LDS tile, no scatter,
// no __syncthreads. Each wave = independent flash over its 16 queries:
//   S^T = K Q^T  (A=K rows from global, B=Q rows held in regs)
//   p = exp(s/8) masked (no max-subtraction: |s|<~6 for unit-normal inputs)
//   P -> wave-private LDS slice (C->B layout), l accumulates per-lane
//   O^T += V^T P^T (A=VT global b128, B=P from LDS)
// LDS 9.2 KB/block; TLP (up to 8 blocks x 4 waves/CU) hides all latency.
// ---------------------------------------------------------------------------
__global__ __launch_bounds__(256)
void attn_mfma(const bf16_t* __restrict__ QK, const bf16_t* __restrict__ VT,
               const int* __restrict__ lens, bf16_t* __restrict__ Z)
{
    __shared__ __align__(16) bf16_t Ps[64][72];   // wave w owns rows [16w,16w+16)

    const int tid  = threadIdx.x;
    const int lane = tid & 63;
    const int w    = tid >> 6;
    const int quad = lane >> 4;
    const int l16  = lane & 15;
    const int qt   = blockIdx.x;
    const int h    = blockIdx.y;
    const int b    = blockIdx.z;
    const int len  = lens[b];
    const int qbase = qt * 64;
    const bf16_t* Qp  = QK + (size_t)b * S_ * 2048 + (size_t)h * 64;
    const bf16_t* Kp  = Qp + 1024;
    const bf16_t* VTp = VT + (size_t)(h * 64) * 8192 + (size_t)b * 1024;
    const size_t zbase = (size_t)b * S_ * D_ + (size_t)h * 64;

    if (qbase >= len) {   // fully masked query tile -> zeros (bf16)
        const int r = tid >> 2, c0 = (tid & 3) * 16;
        bf16_t* zp = Z + zbase + (size_t)(qbase + r) * D_ + c0;
        uint4 zz = {0u, 0u, 0u, 0u};
        *(uint4*)zp = zz;
        *(uint4*)(zp + 8) = zz;
        return;
    }

    // Q B-frags, fixed for the whole kernel: B[k=d=quad*8+j][n=q=l16]
    const int qrow = qbase + w * 16 + l16;
    const bf16x8 bq0 = *(const bf16x8*)(Qp + (size_t)qrow * 2048 + quad * 8);
    const bf16x8 bq1 = *(const bf16x8*)(Qp + (size_t)qrow * 2048 + 32 + quad * 8);

    f32x4 o[4];
    #pragma unroll
    for (int dm = 0; dm < 4; dm++)
        #pragma unroll
        for (int r = 0; r < 4; r++) o[dm][r] = 0.f;
    float l_q = 0.f;

    const int ntiles = (len + 63) >> 6;
    for (int t = 0; t < ntiles; t++) {
        const int k0 = t * 64;

        // ---- S^T = K Q^T, exp, stage P (per kt: MFMA(kt+1) overlaps exp(kt)) ----
        #pragma unroll
        for (int kt = 0; kt < 4; kt++) {
            const bf16_t* krow = Kp + (size_t)(k0 + kt * 16 + l16) * 2048;
            const bf16x8 ak0 = *(const bf16x8*)(krow + quad * 8);
            const bf16x8 ak1 = *(const bf16x8*)(krow + 32 + quad * 8);
            f32x4 z4 = {0.f, 0.f, 0.f, 0.f};
            z4 = __builtin_amdgcn_mfma_f32_16x16x32_bf16(ak0, bq0, z4, 0, 0, 0);
            const f32x4 sfv = __builtin_amdgcn_mfma_f32_16x16x32_bf16(ak1, bq1, z4, 0, 0, 0);
            bf16x4v pk;
            #pragma unroll
            for (int r = 0; r < 4; r++) {
                const int key = k0 + kt * 16 + quad * 4 + r;
                float p = __expf(sfv[r] * 0.125f);
                p = (key < len) ? p : 0.f;
                l_q += p;
                pk[r] = (bf16_t)p;
            }
            *(bf16x4v*)&Ps[w * 16 + l16][kt * 16 + quad * 4] = pk;
        }

        // ---- O^T += V^T P^T ----
        const bf16x8 bp0 = *(const bf16x8*)&Ps[w * 16 + l16][quad * 8];
        const bf16x8 bp1 = *(const bf16x8*)&Ps[w * 16 + l16][32 + quad * 8];
        #pragma unroll
        for (int dm = 0; dm < 4; dm++) {
            const bf16_t* vrow = VTp + (size_t)(dm * 16 + l16) * 8192 + k0;
            const bf16x8 av0 = *(const bf16x8*)(vrow + quad * 8);
            const bf16x8 av1 = *(const bf16x8*)(vrow + 32 + quad * 8);
            o[dm] = __builtin_amdgcn_mfma_f32_16x16x32_bf16(av0, bp0, o[dm], 0, 0, 0);
            o[dm] = __builtin_amdgcn_mfma_f32_16x16x32_bf16(av1, bp1, o[dm], 0, 0, 0);
        }
    }

    // ---- final l reduce + epilogue (O^T col = q = l16, row = d) ----
    l_q += __shfl_xor(l_q, 16);
    l_q += __shfl_xor(l_q, 32);
    const int qg = qbase + w * 16 + l16;
    const float inv = (qg < len) ? 1.f / l_q : 0.f;
    bf16_t* zrow = Z + zbase + (size_t)qg * D_;
    #pragma unroll
    for (int dm = 0; dm < 4; dm++) {
        bf16x4v st;
        #pragma unroll
        for (int r = 0; r < 4; r++) st[r] = (bf16_t)(o[dm][r] * inv);
        *(bf16x4v*)(zrow + dm * 16 + quad * 4) = st;
    }
}

// ---------------------------------------------------------------------------
// Residual-add + LayerNorm, D=1024, one block per row.
// ---------------------------------------------------------------------------
__device__ __forceinline__ void ln_core(float vx, float vy, float vz, float vw,
                                        int tid, float& mean, float& rstd)
{
    __shared__ float red[8];
    float s = vx + vy + vz + vw;
    #pragma unroll
    for (int off = 32; off; off >>= 1) s += __shfl_xor(s, off, 64);
    const int wv = tid >> 6, lane = tid & 63;
    if (lane == 0) red[wv] = s;
    __syncthreads();
    mean = (red[0] + red[1] + red[2] + red[3]) * (1.f / D_);
    const float dx = vx - mean, dy = vy - mean, dz = vz - mean, dw = vw - mean;
    float s2 = dx * dx + dy * dy + dz * dz + dw * dw;
    #pragma unroll
    for (int off = 32; off; off >>= 1) s2 += __shfl_xor(s2, off, 64);
    if (lane == 0) red[4 + wv] = s2;
    __syncthreads();
    rstd = rsqrtf((red[4] + red[5] + red[6] + red[7]) * (1.f / D_) + EPS_);
}

__global__ __launch_bounds__(256)
void add_ln1(const float* __restrict__ X, const bf16_t* __restrict__ Y,
             const float* __restrict__ g, const float* __restrict__ beta,
             bf16_t* __restrict__ out)
{
    const int row = blockIdx.x, tid = threadIdx.x;
    const float4 xv = ((const float4*)(X + (size_t)row * D_))[tid];
    const bf16x4v yv = *(const bf16x4v*)(Y + (size_t)row * D_ + tid * 4);
    const float vx = xv.x + (float)yv[0], vy = xv.y + (float)yv[1];
    const float vz = xv.z + (float)yv[2], vw = xv.w + (float)yv[3];
    float mean, rstd;
    ln_core(vx, vy, vz, vw, tid, mean, rstd);
    const float4 gv = ((const float4*)g)[tid];
    const float4 bv = ((const float4*)beta)[tid];
    bf16x4v o;
    o[0] = (bf16_t)((vx - mean) * rstd * gv.x + bv.x);
    o[1] = (bf16_t)((vy - mean) * rstd * gv.y + bv.y);
    o[2] = (bf16_t)((vz - mean) * rstd * gv.z + bv.z);
    o[3] = (bf16_t)((vw - mean) * rstd * gv.w + bv.w);
    *(bf16x4v*)(out + (size_t)row * D_ + tid * 4) = o;
}

__global__ __launch_bounds__(256)
void add_ln2(const bf16_t* __restrict__ X, const float* __restrict__ Y,
             const float* __restrict__ g, const float* __restrict__ beta,
             float* __restrict__ out)
{
    const int row = blockIdx.x, tid = threadIdx.x;
    const bf16x4v xv = *(const bf16x4v*)(X + (size_t)row * D_ + tid * 4);
    const float4 yv = ((const float4*)(Y + (size_t)row * D_))[tid];
    const float vx = (float)xv[0] + yv.x, vy = (float)xv[1] + yv.y;
    const float vz = (float)xv[2] + yv.z, vw = (float)xv[3] + yv.w;
    float mean, rstd;
    ln_core(vx, vy, vz, vw, tid, mean, rstd);
    const float4 gv = ((const float4*)g)[tid];
    const float4 bv = ((const float4*)beta)[tid];
    float4 o;
    o.x = (vx - mean) * rstd * gv.x + bv.x;
    o.y = (vy - mean) * rstd * gv.y + bv.y;
    o.z = (vz - mean) * rstd * gv.z + bv.z;
    o.w = (vw - mean) * rstd * gv.w + bv.w;
    ((float4*)(out + (size_t)row * D_))[tid] = o;
}

// ---------------------------------------------------------------------------
extern "C" void kernel_launch(void* const* d_in, const int* in_sizes, int n_in,
                              void* d_out, int out_size, void* d_ws, size_t ws_size,
                              hipStream_t stream)
{
    const float* x    = (const float*)d_in[0];
    const float* Wq   = (const float*)d_in[1];
    const float* Wk   = (const float*)d_in[2];
    const float* Wv   = (const float*)d_in[3];
    const float* fc1w = (const float*)d_in[4];
    const float* fc1b = (const float*)d_in[5];
    const float* fc2w = (const float*)d_in[6];
    const float* fc2b = (const float*)d_in[7];
    const float* ln1w = (const float*)d_in[8];
    const float* ln1b = (const float*)d_in[9];
    const float* ln2w = (const float*)d_in[10];
    const float* ln2b = (const float*)d_in[11];
    const int*   lens = (const int*)d_in[12];
    float* out = (float*)d_out;

    char* ws = (char*)d_ws;
    const size_t MB = 1024 * 1024;
    bf16_t* QKb   = (bf16_t*)(ws);              // 32 MB: [8192][2048] Q|K
    bf16_t* VTb   = (bf16_t*)(ws + 32 * MB);    // 16 MB: [1024 hd][8192 tok]
    bf16_t* Zb    = (bf16_t*)(ws + 48 * MB);    // 16 MB
    bf16_t* X1b   = (bf16_t*)(ws + 64 * MB);    // 16 MB
    bf16_t* xb    = (bf16_t*)(ws + 80 * MB);    // 16 MB (dead after projections)
    bf16_t* H1b   = (bf16_t*)(ws + 80 * MB);    //   reuses xb slot
    float*  FF    = (float*)(ws);               //   reuses QKb slot (32 MB, dead after attn)
    bf16_t* WtQKV = (bf16_t*)(ws + 96 * MB);    // 6 MB: [3072][1024]
    bf16_t* Wt1   = (bf16_t*)(ws + 102 * MB);   // 2 MB
    bf16_t* Wt2   = (bf16_t*)(ws + 104 * MB);   // 2 MB
    // total 106 MB

    const int M = B_ * S_;

    prep<<<dim3(16, 16, 37), 256, 0, stream>>>(x, Wq, Wk, Wv, fc1w, fc2w,
                                               xb, WtQKV, Wt1, Wt2);

    // Q|K projection: [8192][2048]
    gemm_mfma<0, bf16_t><<<dim3(2048 / 128, M / 128), 256, 0, stream>>>(
        xb, WtQKV, nullptr, nullptr, QKb, M, 2048, D_);
    // V projection, TRANSPOSED output: VT[hd][token] = WtV . xb^T
    gemm_mfma<0, bf16_t><<<dim3(M / 128, D_ / 128), 256, 0, stream>>>(
        WtQKV + (size_t)2048 * D_, xb, nullptr, nullptr, VTb, D_, M, D_);

    attn_mfma<<<dim3(S_ / 64, H_, B_), 256, 0, stream>>>(QKb, VTb, lens, Zb);

    add_ln1<<<M, 256, 0, stream>>>(x, Zb, ln1w, ln1b, X1b);

    gemm_mfma<1, bf16_t><<<dim3(D_ / 128, M / 128), 256, 0, stream>>>(
        X1b, Wt1, fc1b, lens, H1b, M, D_, D_);
    gemm_mfma<2, float><<<dim3(D_ / 128, M / 128), 256, 0, stream>>>(
        H1b, Wt2, fc2b, lens, FF, M, D_, D_);

    add_ln2<<<M, 256, 0, stream>>>(X1b, FF, ln2w, ln2b, out);
}

// Round 7
// 378.132 us; speedup vs baseline: 1.2092x; 1.2092x over previous
//
#include <hip/hip_runtime.h>
#include <math.h>

#define B_ 8
#define S_ 1024
#define D_ 1024
#define H_ 16
#define DK_ 64
#define EPS_ 1e-5f

typedef __bf16 bf16_t;
typedef __bf16 bf16x8 __attribute__((ext_vector_type(8)));
typedef __bf16 bf16x4v __attribute__((ext_vector_type(4)));
typedef float  f32x4  __attribute__((ext_vector_type(4)));

__device__ __forceinline__ void gld16(const void* g, void* l) {
    __builtin_amdgcn_global_load_lds(
        (const __attribute__((address_space(1))) void*)g,
        (__attribute__((address_space(3))) void*)l, 16, 0, 0);
}

// ---------------------------------------------------------------------------
// prep: fused weight transpose+convert (z=0..4) and x f32->bf16 (z=5..36).
// ---------------------------------------------------------------------------
__global__ __launch_bounds__(256)
void prep(const float* __restrict__ x,
          const float* __restrict__ Wq, const float* __restrict__ Wk,
          const float* __restrict__ Wv, const float* __restrict__ W1,
          const float* __restrict__ W2, bf16_t* __restrict__ xb,
          bf16_t* __restrict__ WtQKV, bf16_t* __restrict__ Wt1,
          bf16_t* __restrict__ Wt2)
{
    __shared__ float tile[64][65];
    const int tid = threadIdx.x;
    const int z = blockIdx.z;

    if (z >= 5) {   // x convert
        const int blk = (z - 5) * 256 + blockIdx.y * 16 + blockIdx.x;
        const int i = (blk * 256 + tid) * 4;
        const float4 v = *(const float4*)(x + i);
        bf16x4v o = { (bf16_t)v.x, (bf16_t)v.y, (bf16_t)v.z, (bf16_t)v.w };
        *(bf16x4v*)(xb + i) = o;
        return;
    }

    const int n0 = blockIdx.x * 64, k0 = blockIdx.y * 64;
    const int col = tid & 63, r0 = tid >> 6;
    const float* src = (z == 0) ? Wq : (z == 1) ? Wk : (z == 2) ? Wv
                     : (z == 3) ? W1 : W2;
    #pragma unroll
    for (int i = 0; i < 16; i++) {
        const int row = r0 + i * 4;
        float v;
        if (z < 3)
            v = src[((size_t)(n0 >> 6) << 16) + (size_t)(k0 + row) * 64 + col];
        else
            v = src[(size_t)(k0 + row) * D_ + n0 + col];
        tile[row][col] = v;
    }
    __syncthreads();
    bf16_t* dst = (z < 3) ? (WtQKV + (size_t)z * D_ * D_)
                : (z == 3) ? Wt1 : Wt2;
    #pragma unroll
    for (int i = 0; i < 16; i++) {
        const int nr = r0 + i * 4;
        dst[(size_t)(n0 + nr) * D_ + k0 + col] = (bf16_t)tile[col][nr];
    }
}

// ---------------------------------------------------------------------------
// bf16 MFMA GEMM, m97 structure (128x128, BK=32, global_load_lds w=16,
// chunk-XOR swizzle). EPI: 0 plain; 1 +bias,relu,mask; 2 +bias,mask.
// ---------------------------------------------------------------------------
template<int EPI, typename OUT>
__global__ __launch_bounds__(256)
void gemm_mfma(const bf16_t* __restrict__ A, const bf16_t* __restrict__ Bw,
               const float* __restrict__ bias, const int* __restrict__ lens,
               OUT* __restrict__ C, int M, int N, int K)
{
    __shared__ bf16_t As[128 * 32];
    __shared__ bf16_t Bs[128 * 32];
    const int tid  = threadIdx.x;
    const int lane = tid & 63;
    const int w    = tid >> 6;
    const int quad = lane >> 4, l16 = lane & 15;
    const int wm = w & 1, wn = w >> 1;
    const int bn = blockIdx.x * 128, bm = blockIdx.y * 128;

    f32x4 acc[4][4];
    #pragma unroll
    for (int i = 0; i < 4; i++)
        #pragma unroll
        for (int j = 0; j < 4; j++)
            #pragma unroll
            for (int r = 0; r < 4; r++) acc[i][j][r] = 0.f;

    const int fsw = (quad ^ (l16 ^ (l16 >> 2))) & 3;

    for (int k0 = 0; k0 < K; k0 += 32) {
        #pragma unroll
        for (int j = 0; j < 2; j++) {
            const int chunk = j * 256 + tid;
            const int m = chunk >> 2, cs = chunk & 3;
            const int cg = cs ^ ((m ^ (m >> 2)) & 3);
            gld16(A + (size_t)(bm + m) * K + k0 + cg * 8,
                  (char*)As + (size_t)(j * 256 + w * 64) * 16);
            gld16(Bw + (size_t)(bn + m) * K + k0 + cg * 8,
                  (char*)Bs + (size_t)(j * 256 + w * 64) * 16);
        }
        __syncthreads();

        bf16x8 a[4], b[4];
        #pragma unroll
        for (int i = 0; i < 4; i++)
            a[i] = *(const bf16x8*)&As[(wm * 64 + i * 16 + l16) * 32 + fsw * 8];
        #pragma unroll
        for (int j = 0; j < 4; j++)
            b[j] = *(const bf16x8*)&Bs[(wn * 64 + j * 16 + l16) * 32 + fsw * 8];
        #pragma unroll
        for (int i = 0; i < 4; i++)
            #pragma unroll
            for (int j = 0; j < 4; j++)
                acc[i][j] = __builtin_amdgcn_mfma_f32_16x16x32_bf16(a[i], b[j], acc[i][j], 0, 0, 0);
        __syncthreads();
    }

    #pragma unroll
    for (int i = 0; i < 4; i++) {
        #pragma unroll
        for (int r = 0; r < 4; r++) {
            const int m = bm + wm * 64 + i * 16 + quad * 4 + r;
            float keep = 1.f;
            if (EPI != 0) {
                const int s = m & (S_ - 1);
                const int bb = m >> 10;
                keep = (s < lens[bb]) ? 1.f : 0.f;
            }
            #pragma unroll
            for (int j = 0; j < 4; j++) {
                const int n = bn + wn * 64 + j * 16 + l16;
                float v = acc[i][j][r];
                if (EPI != 0) {
                    v += bias[n];
                    if (EPI == 1) v = fmaxf(v, 0.f);
                    v *= keep;
                }
                C[(size_t)m * N + n] = (OUT)v;
            }
        }
    }
}

// ---------------------------------------------------------------------------
// bf16 MFMA flash attention, S^T formulation (R5 structure, tuned):
//   - SINGLE-buffer Vt + 2 barriers/iter: LDS 18.4 KB -> 8 blocks/CU
//     (vs R5's dbuf 27.6 KB -> 5; the dbuf's prefetch was compiler-sunk).
//   - V global loads issued FIRST, consumed (scatter) AFTER the whole
//     QK^T+exp+Ps section: ~400 cyc of V latency hidden behind QK work.
//   - 1D grid, b-fastest swizzle: every CU gets an even mix of batch
//     lengths (work ~ len^2; b-major ordering skewed CU loads).
//   - No max-subtraction softmax (|s|<~6): p=exp(s/8), one l-reduce at end.
// ---------------------------------------------------------------------------
__global__ __launch_bounds__(256)
void attn_mfma(const bf16_t* __restrict__ QKV, const int* __restrict__ lens,
               bf16_t* __restrict__ Z)
{
    __shared__ __align__(16) bf16_t Vt[64][72];   // [d][key ^ 16*(d>>4)]
    __shared__ __align__(16) bf16_t Ps[64][72];   // [q][key], wave-private rows

    const int tid  = threadIdx.x;
    const int lane = tid & 63;
    const int w    = tid >> 6;
    const int quad = lane >> 4;
    const int l16  = lane & 15;
    const int id   = blockIdx.x;
    const int b    = id & 7;            // b fastest -> CU-load balance
    const int h    = (id >> 3) & 15;
    const int qt   = id >> 7;
    const int len  = lens[b];
    const int qbase = qt * 64;
    const bf16_t* Qp = QKV + (size_t)b * S_ * 3072 + (size_t)h * 64;
    const bf16_t* Kp = Qp + 1024;
    const bf16_t* Vp = Qp + 2048;
    const size_t zbase = (size_t)b * S_ * D_ + (size_t)h * 64;

    if (qbase >= len) {   // fully masked query tile -> zeros (bf16)
        const int r = tid >> 2, c0 = (tid & 3) * 16;
        bf16_t* zp = Z + zbase + (size_t)(qbase + r) * D_ + c0;
        uint4 zz = {0u, 0u, 0u, 0u};
        *(uint4*)zp = zz;
        *(uint4*)(zp + 8) = zz;
        return;
    }

    // Q B-frags, fixed for the whole kernel: B[k=d=quad*8+j][n=q=l16]
    const int qrow = qbase + w * 16 + l16;
    const bf16x8 bq0 = *(const bf16x8*)(Qp + (size_t)qrow * 3072 + quad * 8);
    const bf16x8 bq1 = *(const bf16x8*)(Qp + (size_t)qrow * 3072 + 32 + quad * 8);

    // V staging map: thread -> key row vr, d cols vc0..vc0+15, swizzled col vp
    const int vr  = tid >> 2;
    const int vc0 = (tid & 3) * 16;
    const int vp  = vr ^ ((tid & 3) << 4);

    f32x4 o[4];
    #pragma unroll
    for (int dm = 0; dm < 4; dm++)
        #pragma unroll
        for (int r = 0; r < 4; r++) o[dm][r] = 0.f;
    float l_q = 0.f;

    const int ntiles = (len + 63) >> 6;
    for (int t = 0; t < ntiles; t++) {
        const int k0 = t * 64;

        // ---- issue V loads (consumed only after the QK section) ----
        const bf16_t* vsrc = Vp + (size_t)(k0 + vr) * 3072 + vc0;
        const bf16x8 v0 = *(const bf16x8*)vsrc;
        const bf16x8 v1 = *(const bf16x8*)(vsrc + 8);

        // ---- S^T = K Q^T, exp, stage P ----
        #pragma unroll
        for (int kt = 0; kt < 4; kt++) {
            const bf16_t* krow = Kp + (size_t)(k0 + kt * 16 + l16) * 3072;
            const bf16x8 ak0 = *(const bf16x8*)(krow + quad * 8);
            const bf16x8 ak1 = *(const bf16x8*)(krow + 32 + quad * 8);
            f32x4 z4 = {0.f, 0.f, 0.f, 0.f};
            z4 = __builtin_amdgcn_mfma_f32_16x16x32_bf16(ak0, bq0, z4, 0, 0, 0);
            const f32x4 sfv = __builtin_amdgcn_mfma_f32_16x16x32_bf16(ak1, bq1, z4, 0, 0, 0);
            bf16x4v pk;
            #pragma unroll
            for (int r = 0; r < 4; r++) {
                const int key = k0 + kt * 16 + quad * 4 + r;
                float p = __expf(sfv[r] * 0.125f);
                p = (key < len) ? p : 0.f;
                l_q += p;
                pk[r] = (bf16_t)p;
            }
            *(bf16x4v*)&Ps[w * 16 + l16][kt * 16 + quad * 4] = pk;
        }

        // ---- scatter V -> Vt (transposed + XOR swizzle), then barrier ----
        #pragma unroll
        for (int i = 0; i < 8; i++) Vt[vc0 + i][vp] = v0[i];
        #pragma unroll
        for (int i = 0; i < 8; i++) Vt[vc0 + 8 + i][vp] = v1[i];
        __syncthreads();

        // ---- O^T += V^T P^T ----
        const bf16x8 bp0 = *(const bf16x8*)&Ps[w * 16 + l16][quad * 8];
        const bf16x8 bp1 = *(const bf16x8*)&Ps[w * 16 + l16][32 + quad * 8];
        #pragma unroll
        for (int dm = 0; dm < 4; dm++) {
            const bf16x8 av0 = *(const bf16x8*)&Vt[dm * 16 + l16][(quad * 8) ^ (dm * 16)];
            const bf16x8 av1 = *(const bf16x8*)&Vt[dm * 16 + l16][(32 + quad * 8) ^ (dm * 16)];
            o[dm] = __builtin_amdgcn_mfma_f32_16x16x32_bf16(av0, bp0, o[dm], 0, 0, 0);
            o[dm] = __builtin_amdgcn_mfma_f32_16x16x32_bf16(av1, bp1, o[dm], 0, 0, 0);
        }
        __syncthreads();   // protect Vt before next iter's scatter
    }

    // ---- final l reduce + epilogue ----
    l_q += __shfl_xor(l_q, 16);
    l_q += __shfl_xor(l_q, 32);
    const int qg = qbase + w * 16 + l16;
    const float inv = (qg < len) ? 1.f / l_q : 0.f;
    bf16_t* zrow = Z + zbase + (size_t)qg * D_;
    #pragma unroll
    for (int dm = 0; dm < 4; dm++) {
        bf16x4v st;
        #pragma unroll
        for (int r = 0; r < 4; r++) st[r] = (bf16_t)(o[dm][r] * inv);
        *(bf16x4v*)(zrow + dm * 16 + quad * 4) = st;
    }
}

// ---------------------------------------------------------------------------
// Residual-add + LayerNorm, D=1024, one block per row.
// ---------------------------------------------------------------------------
__device__ __forceinline__ void ln_core(float vx, float vy, float vz, float vw,
                                        int tid, float& mean, float& rstd)
{
    __shared__ float red[8];
    float s = vx + vy + vz + vw;
    #pragma unroll
    for (int off = 32; off; off >>= 1) s += __shfl_xor(s, off, 64);
    const int wv = tid >> 6, lane = tid & 63;
    if (lane == 0) red[wv] = s;
    __syncthreads();
    mean = (red[0] + red[1] + red[2] + red[3]) * (1.f / D_);
    const float dx = vx - mean, dy = vy - mean, dz = vz - mean, dw = vw - mean;
    float s2 = dx * dx + dy * dy + dz * dz + dw * dw;
    #pragma unroll
    for (int off = 32; off; off >>= 1) s2 += __shfl_xor(s2, off, 64);
    if (lane == 0) red[4 + wv] = s2;
    __syncthreads();
    rstd = rsqrtf((red[4] + red[5] + red[6] + red[7]) * (1.f / D_) + EPS_);
}

__global__ __launch_bounds__(256)
void add_ln1(const float* __restrict__ X, const bf16_t* __restrict__ Y,
             const float* __restrict__ g, const float* __restrict__ beta,
             bf16_t* __restrict__ out)
{
    const int row = blockIdx.x, tid = threadIdx.x;
    const float4 xv = ((const float4*)(X + (size_t)row * D_))[tid];
    const bf16x4v yv = *(const bf16x4v*)(Y + (size_t)row * D_ + tid * 4);
    const float vx = xv.x + (float)yv[0], vy = xv.y + (float)yv[1];
    const float vz = xv.z + (float)yv[2], vw = xv.w + (float)yv[3];
    float mean, rstd;
    ln_core(vx, vy, vz, vw, tid, mean, rstd);
    const float4 gv = ((const float4*)g)[tid];
    const float4 bv = ((const float4*)beta)[tid];
    bf16x4v o;
    o[0] = (bf16_t)((vx - mean) * rstd * gv.x + bv.x);
    o[1] = (bf16_t)((vy - mean) * rstd * gv.y + bv.y);
    o[2] = (bf16_t)((vz - mean) * rstd * gv.z + bv.z);
    o[3] = (bf16_t)((vw - mean) * rstd * gv.w + bv.w);
    *(bf16x4v*)(out + (size_t)row * D_ + tid * 4) = o;
}

__global__ __launch_bounds__(256)
void add_ln2(const bf16_t* __restrict__ X, const float* __restrict__ Y,
             const float* __restrict__ g, const float* __restrict__ beta,
             float* __restrict__ out)
{
    const int row = blockIdx.x, tid = threadIdx.x;
    const bf16x4v xv = *(const bf16x4v*)(X + (size_t)row * D_ + tid * 4);
    const float4 yv = ((const float4*)(Y + (size_t)row * D_))[tid];
    const float vx = (float)xv[0] + yv.x, vy = (float)xv[1] + yv.y;
    const float vz = (float)xv[2] + yv.z, vw = (float)xv[3] + yv.w;
    float mean, rstd;
    ln_core(vx, vy, vz, vw, tid, mean, rstd);
    const float4 gv = ((const float4*)g)[tid];
    const float4 bv = ((const float4*)beta)[tid];
    float4 o;
    o.x = (vx - mean) * rstd * gv.x + bv.x;
    o.y = (vy - mean) * rstd * gv.y + bv.y;
    o.z = (vz - mean) * rstd * gv.z + bv.z;
    o.w = (vw - mean) * rstd * gv.w + bv.w;
    ((float4*)(out + (size_t)row * D_))[tid] = o;
}

// ---------------------------------------------------------------------------
extern "C" void kernel_launch(void* const* d_in, const int* in_sizes, int n_in,
                              void* d_out, int out_size, void* d_ws, size_t ws_size,
                              hipStream_t stream)
{
    const float* x    = (const float*)d_in[0];
    const float* Wq   = (const float*)d_in[1];
    const float* Wk   = (const float*)d_in[2];
    const float* Wv   = (const float*)d_in[3];
    const float* fc1w = (const float*)d_in[4];
    const float* fc1b = (const float*)d_in[5];
    const float* fc2w = (const float*)d_in[6];
    const float* fc2b = (const float*)d_in[7];
    const float* ln1w = (const float*)d_in[8];
    const float* ln1b = (const float*)d_in[9];
    const float* ln2w = (const float*)d_in[10];
    const float* ln2b = (const float*)d_in[11];
    const int*   lens = (const int*)d_in[12];
    float* out = (float*)d_out;

    char* ws = (char*)d_ws;
    const size_t MB = 1024 * 1024;
    bf16_t* QKVb  = (bf16_t*)(ws);              // 48 MB: [8192][3072]
    bf16_t* Zb    = (bf16_t*)(ws + 48 * MB);    // 16 MB: [8192][1024] bf16
    bf16_t* X1b   = (bf16_t*)(ws + 80 * MB);    // 16 MB
    bf16_t* xb    = (bf16_t*)(ws + 96 * MB);    // 16 MB (dead after QKV)
    bf16_t* H1b   = (bf16_t*)(ws + 96 * MB);    //   reuses xb slot
    float*  FF    = (float*)(ws + 48 * MB);     //   reuses Zb slot (32 MB)
    bf16_t* WtQKV = (bf16_t*)(ws + 112 * MB);   // 6 MB
    bf16_t* Wt1   = (bf16_t*)(ws + 118 * MB);   // 2 MB
    bf16_t* Wt2   = (bf16_t*)(ws + 120 * MB);   // 2 MB

    const int M = B_ * S_;

    prep<<<dim3(16, 16, 37), 256, 0, stream>>>(x, Wq, Wk, Wv, fc1w, fc2w,
                                               xb, WtQKV, Wt1, Wt2);

    gemm_mfma<0, bf16_t><<<dim3(3072 / 128, M / 128), 256, 0, stream>>>(
        xb, WtQKV, nullptr, nullptr, QKVb, M, 3072, D_);

    attn_mfma<<<dim3(2048), 256, 0, stream>>>(QKVb, lens, Zb);

    add_ln1<<<M, 256, 0, stream>>>(x, Zb, ln1w, ln1b, X1b);

    gemm_mfma<1, bf16_t><<<dim3(D_ / 128, M / 128), 256, 0, stream>>>(
        X1b, Wt1, fc1b, lens, H1b, M, D_, D_);
    gemm_mfma<2, float><<<dim3(D_ / 128, M / 128), 256, 0, stream>>>(
        H1b, Wt2, fc2b, lens, FF, M, D_, D_);

    add_ln2<<<M, 256, 0, stream>>>(X1b, FF, ln2w, ln2b, out);
}